// Round 2
// baseline (189.035 us; speedup 1.0000x reference)
//
#include <hip/hip_runtime.h>

#define B_DIM 8
#define M_MICS 8
#define F_DIM 257
#define T_DIM 2000
#define NPROB (B_DIM * F_DIM)            // 2056
#define COV_STRIDE 144                    // floats per (prob, time-chunk)
#define NCHUNKT 2
#define COV_FLOATS (NPROB * NCHUNKT * COV_STRIDE)
#define W_OFFSET COV_FLOATS
#define WS_FLOATS (COV_FLOATS + NPROB * 16)

// ============================ K1: covariance =================================
// grid (F, B, 2 time-chunks), 256 threads.
// tid>>7 selects pair-half: h0 = msums + diag + pairs q<14 (74 acc),
// h1 = pairs q in [14,28) (56 acc). Both halves stream the SAME t-samples
// (h1's loads are L1/L2 hits). Compact acc layouts; partials -> ws.
__launch_bounds__(256, 4)
__global__ void cov_kernel(const float* __restrict__ sre, const float* __restrict__ sim,
                           const float* __restrict__ smask, const float* __restrict__ nmask,
                           float* __restrict__ wscov)
{
    const int f = blockIdx.x, b = blockIdx.y, c = blockIdx.z;
    const int tid = threadIdx.x;
    const int h = tid >> 7;        // wave-uniform (waves 0,1 vs 2,3)
    const int s = tid & 127;

    const size_t mrow = (size_t)F_DIM * T_DIM;
    const size_t base_bf = ((size_t)(b * M_MICS) * F_DIM + f) * T_DIM + (size_t)c * 1000;
    const size_t mbase   = ((size_t)b * F_DIM + f) * T_DIM + (size_t)c * 1000;

    float acc[80];
#pragma unroll
    for (int i = 0; i < 80; ++i) acc[i] = 0.f;

    for (int g = 0; g < 4; ++g) {
        const int t0 = 2 * s + 256 * g;
        if (t0 < 1000) {
            const float2 ms2 = *reinterpret_cast<const float2*>(smask + mbase + t0);
            const float2 mn2 = *reinterpret_cast<const float2*>(nmask + mbase + t0);
            const float msv[2] = { ms2.x, ms2.y };
            const float mnv[2] = { mn2.x, mn2.y };
            if (h == 0) {
                float yr[8][2], yi[8][2];
#pragma unroll
                for (int m = 0; m < 8; ++m) {
                    const float2 vr = *reinterpret_cast<const float2*>(sre + base_bf + (size_t)m * mrow + t0);
                    const float2 vi = *reinterpret_cast<const float2*>(sim + base_bf + (size_t)m * mrow + t0);
                    yr[m][0] = vr.x; yr[m][1] = vr.y;
                    yi[m][0] = vi.x; yi[m][1] = vi.y;
                }
#pragma unroll
                for (int u = 0; u < 2; ++u) {
                    acc[0] += msv[u];
                    acc[1] += mnv[u];
#pragma unroll
                    for (int m = 0; m < 8; ++m) {
                        const float pd = yr[m][u] * yr[m][u] + yi[m][u] * yi[m][u];
                        acc[2 + m]  += msv[u] * pd;
                        acc[10 + m] += mnv[u] * pd;
                    }
#pragma unroll
                    for (int m = 0; m < 8; ++m) {
#pragma unroll
                        for (int n = m + 1; n < 8; ++n) {
                            const int q = m * 8 - m * (m + 1) / 2 + n - m - 1;
                            if (q < 14) {
                                const float pr = yr[m][u] * yr[n][u] + yi[m][u] * yi[n][u];
                                const float pi = yi[m][u] * yr[n][u] - yr[m][u] * yi[n][u];
                                acc[18 + 4 * q + 0] += msv[u] * pr;
                                acc[18 + 4 * q + 1] += msv[u] * pi;
                                acc[18 + 4 * q + 2] += mnv[u] * pr;
                                acc[18 + 4 * q + 3] += mnv[u] * pi;
                            }
                        }
                    }
                }
            } else {
                float yr[6][2], yi[6][2];   // mics 2..7 only
#pragma unroll
                for (int m = 2; m < 8; ++m) {
                    const float2 vr = *reinterpret_cast<const float2*>(sre + base_bf + (size_t)m * mrow + t0);
                    const float2 vi = *reinterpret_cast<const float2*>(sim + base_bf + (size_t)m * mrow + t0);
                    yr[m - 2][0] = vr.x; yr[m - 2][1] = vr.y;
                    yi[m - 2][0] = vi.x; yi[m - 2][1] = vi.y;
                }
#pragma unroll
                for (int u = 0; u < 2; ++u) {
#pragma unroll
                    for (int m = 2; m < 8; ++m) {
#pragma unroll
                        for (int n = m + 1; n < 8; ++n) {
                            const int q = m * 8 - m * (m + 1) / 2 + n - m - 1;
                            if (q >= 14) {
                                const float pr = yr[m - 2][u] * yr[n - 2][u] + yi[m - 2][u] * yi[n - 2][u];
                                const float pi = yi[m - 2][u] * yr[n - 2][u] - yr[m - 2][u] * yi[n - 2][u];
                                acc[4 * (q - 14) + 0] += msv[u] * pr;
                                acc[4 * (q - 14) + 1] += msv[u] * pi;
                                acc[4 * (q - 14) + 2] += mnv[u] * pr;
                                acc[4 * (q - 14) + 3] += mnv[u] * pi;
                            }
                        }
                    }
                }
            }
        }
    }

    // ---- block reduction: per half, 80 floats over 128 threads ----
    __shared__ float sred[2][128][17];
    __shared__ float spart[2][8][17];
    __shared__ float sout[2][80];
#pragma unroll
    for (int chunk = 0; chunk < 5; ++chunk) {
#pragma unroll
        for (int i = 0; i < 16; ++i) sred[h][s][i] = acc[chunk * 16 + i];
        __syncthreads();
        {
            const int col = s & 15, grp = s >> 4;   // 8 groups of 16
            float v = 0.f;
#pragma unroll
            for (int rr = 0; rr < 16; ++rr) v += sred[h][grp * 16 + rr][col];
            spart[h][grp][col] = v;
        }
        __syncthreads();
        if (s < 16) {
            float v = 0.f;
#pragma unroll
            for (int gp = 0; gp < 8; ++gp) v += spart[h][gp][s];
            sout[h][chunk * 16 + s] = v;
        }
        __syncthreads();
    }

    const size_t wbase = ((size_t)(b * F_DIM + f) * NCHUNKT + c) * COV_STRIDE;
    if (tid < 80)       wscov[wbase + tid] = sout[0][tid];
    else if (tid < 144) wscov[wbase + tid] = sout[1][tid - 80];
}

// ============================ K2: solve ======================================
// 4 problems per block, one 64-lane wave each. lane = (r, c) of the 8x8.
__launch_bounds__(256, 4)
__global__ void solve_kernel(const float* __restrict__ wscov, float* __restrict__ wsw)
{
    const int tid = threadIdx.x;
    const int w = tid >> 6, lane = tid & 63;
    const int p = blockIdx.x * 4 + w;

    __shared__ float sPhi[4][144];
    const size_t cb = (size_t)p * (NCHUNKT * COV_STRIDE);
    for (int i = lane; i < 144; i += 64)
        sPhi[w][i] = wscov[cb + i] + wscov[cb + COV_STRIDE + i];
    __syncthreads();

    const int r = lane >> 3, cc = lane & 7;
    const float Ssum = sPhi[w][0] + 1e-8f;
    const float Nsum = sPhi[w][1] + 1e-8f;

    float ssr, ssi, ar, ai;
    if (r == cc) {
        ssr = sPhi[w][2 + r] / Ssum;  ssi = 0.f;
        ar  = sPhi[w][10 + r] / Nsum + 1e-5f;  ai = 0.f;
    } else {
        const int mm = (r < cc) ? r : cc;
        const int nn2 = (r < cc) ? cc : r;
        const int q = mm * 8 - mm * (mm + 1) / 2 + nn2 - mm - 1;
        const int basei = (q < 14) ? (18 + 4 * q) : (80 + 4 * (q - 14));
        const float sgn = (r < cc) ? 1.f : -1.f;
        ssr = sPhi[w][basei] / Ssum;
        ssi = sgn * sPhi[w][basei + 1] / Ssum;
        ar  = sPhi[w][basei + 2] / Nsum;
        ai  = sgn * sPhi[w][basei + 3] / Nsum;
    }

    // Gauss-Jordan inverse of Phi_nn
    float br = (r == cc) ? 1.f : 0.f, bi = 0.f;
    for (int k = 0; k < 8; ++k) {
        const float pr = __shfl(ar, k * 9, 64);
        const float pi = __shfl(ai, k * 9, 64);
        const float den = pr * pr + pi * pi;
        const float qr = pr / den, qi = -pi / den;
        const bool isk = (r == k);
        const float ar2 = ar * qr - ai * qi;
        const float ai2 = ar * qi + ai * qr;
        const float br2 = br * qr - bi * qi;
        const float bi2 = br * qi + bi * qr;
        ar = isk ? ar2 : ar; ai = isk ? ai2 : ai;
        br = isk ? br2 : br; bi = isk ? bi2 : bi;
        const float rar = __shfl(ar, k * 8 + cc, 64);
        const float rai = __shfl(ai, k * 8 + cc, 64);
        const float rbr = __shfl(br, k * 8 + cc, 64);
        const float rbi = __shfl(bi, k * 8 + cc, 64);
        const float fr = __shfl(ar, r * 8 + k, 64);
        const float fi = __shfl(ai, r * 8 + k, 64);
        const float uar = ar - (fr * rar - fi * rai);
        const float uai = ai - (fr * rai + fi * rar);
        const float ubr = br - (fr * rbr - fi * rbi);
        const float ubi = bi - (fr * rbi + fi * rbr);
        ar = isk ? ar : uar; ai = isk ? ai : uai;
        br = isk ? br : ubr; bi = isk ? bi : ubi;
    }

    // G = Phi_nn_inv @ Phi_ss
    float gr = 0.f, gi = 0.f;
    for (int k = 0; k < 8; ++k) {
        const float ir = __shfl(br, r * 8 + k, 64);
        const float ii = __shfl(bi, r * 8 + k, 64);
        const float skr = __shfl(ssr, k * 8 + cc, 64);
        const float ski = __shfl(ssi, k * 8 + cc, 64);
        gr += ir * skr - ii * ski;
        gi += ir * ski + ii * skr;
    }

    // power iteration
    float vr = 1.f, vi = 0.f;
    for (int it = 0; it < 30; ++it) {
        float wr2 = gr * vr - gi * vi;
        float wi2 = gr * vi + gi * vr;
        wr2 += __shfl_xor(wr2, 1, 64); wi2 += __shfl_xor(wi2, 1, 64);
        wr2 += __shfl_xor(wr2, 2, 64); wi2 += __shfl_xor(wi2, 2, 64);
        wr2 += __shfl_xor(wr2, 4, 64); wi2 += __shfl_xor(wi2, 4, 64);
        float nrm = wr2 * wr2 + wi2 * wi2;
        nrm += __shfl_xor(nrm, 8, 64);
        nrm += __shfl_xor(nrm, 16, 64);
        nrm += __shfl_xor(nrm, 32, 64);
        const float inv = 1.f / (sqrtf(nrm) + 1e-12f);
        wr2 *= inv; wi2 *= inv;
        vr = __shfl(wr2, cc * 9, 64);
        vi = __shfl(wi2, cc * 9, 64);
    }

    const float v0r = __shfl(vr, 0, 64) + 1e-8f;
    const float v0i = __shfl(vi, 0, 64);
    const float dd = v0r * v0r + v0i * v0i;
    const float rtr = (vr * v0r + vi * v0i) / dd;
    const float rti = (vi * v0r - vr * v0i) / dd;

    float dr = br * rtr - bi * rti;
    float di = br * rti + bi * rtr;
    dr += __shfl_xor(dr, 1, 64); di += __shfl_xor(di, 1, 64);
    dr += __shfl_xor(dr, 2, 64); di += __shfl_xor(di, 2, 64);
    dr += __shfl_xor(dr, 4, 64); di += __shfl_xor(di, 4, 64);

    float qden = (r == cc) ? (rtr * dr + rti * di) : 0.f;
    qden += __shfl_xor(qden, 1, 64); qden += __shfl_xor(qden, 2, 64);
    qden += __shfl_xor(qden, 4, 64); qden += __shfl_xor(qden, 8, 64);
    qden += __shfl_xor(qden, 16, 64); qden += __shfl_xor(qden, 32, 64);
    qden += 1e-8f;

    if (cc == 0) {
        wsw[p * 16 + r]     = dr / qden;
        wsw[p * 16 + 8 + r] = di / qden;
    }
}

// ============================ K3: apply ======================================
__launch_bounds__(256, 8)
__global__ void apply_kernel(const float* __restrict__ sre, const float* __restrict__ sim,
                             const float* __restrict__ wsw, float* __restrict__ out, int out_mode)
{
    const int f = blockIdx.x, b = blockIdx.y, z = blockIdx.z;
    const int tid = threadIdx.x;
    __shared__ float sW[16];
    const int p = b * F_DIM + f;
    if (tid < 16) sW[tid] = wsw[p * 16 + tid];
    __syncthreads();

    const int t0 = z * 512 + 2 * tid;
    if (t0 >= T_DIM) return;

    const size_t mrow = (size_t)F_DIM * T_DIM;
    const size_t base_bf = ((size_t)(b * M_MICS) * F_DIM + f) * T_DIM;
    const size_t mbase   = ((size_t)b * F_DIM + f) * T_DIM;

    float er0 = 0.f, ei0 = 0.f, er1 = 0.f, ei1 = 0.f;
#pragma unroll
    for (int m = 0; m < 8; ++m) {
        const float2 vr2 = *reinterpret_cast<const float2*>(sre + base_bf + (size_t)m * mrow + t0);
        const float2 vi2 = *reinterpret_cast<const float2*>(sim + base_bf + (size_t)m * mrow + t0);
        const float wr = sW[m], wi = sW[8 + m];
        er0 += wr * vr2.x + wi * vi2.x;
        ei0 += wr * vi2.x - wi * vr2.x;
        er1 += wr * vr2.y + wi * vi2.y;
        ei1 += wr * vi2.y - wi * vr2.y;
    }
    if (out_mode == 2) {
        *reinterpret_cast<float4*>(out + 2 * (mbase + t0)) = make_float4(er0, ei0, er1, ei1);
    } else {
        *reinterpret_cast<float2*>(out + mbase + t0) = make_float2(er0, er1);
    }
}

// ================= fallback: round-1 fused kernel (known-good) ===============
#define UP(m,n) ((m)*8 - (m)*((m)+1)/2 + (n))
#define UPI(m,n) (UP(m,n) - (m) - 1)
#define NACC 144
#define NCHUNK 9

__launch_bounds__(256, 2)
__global__ void mvdr_fused_kernel(const float* __restrict__ sre, const float* __restrict__ sim,
                                  const float* __restrict__ smask, const float* __restrict__ nmask,
                                  float* __restrict__ out, int out_mode)
{
    const int f = blockIdx.x;
    const int b = blockIdx.y;
    const int tid = threadIdx.x;

    __shared__ float sred[256 * 20];
    __shared__ float spart[16 * 17];
    __shared__ float sPhi[NACC];
    __shared__ float sW[16];

    const size_t mrow = (size_t)F_DIM * T_DIM;
    const size_t base_bf = ((size_t)(b * M_MICS) * F_DIM + f) * T_DIM;
    const size_t mbase = ((size_t)b * F_DIM + f) * T_DIM;

    float acc[NACC];
#pragma unroll
    for (int i = 0; i < NACC; ++i) acc[i] = 0.f;

    for (int g = 0; g < 4; ++g) {
        const int t0 = g * 512 + 2 * tid;
        if (t0 < T_DIM) {
            float yr[M_MICS][2], yi[M_MICS][2];
#pragma unroll
            for (int m = 0; m < M_MICS; ++m) {
                const float2 vr = *reinterpret_cast<const float2*>(sre + base_bf + (size_t)m * mrow + t0);
                const float2 vi = *reinterpret_cast<const float2*>(sim + base_bf + (size_t)m * mrow + t0);
                yr[m][0] = vr.x; yr[m][1] = vr.y;
                yi[m][0] = vi.x; yi[m][1] = vi.y;
            }
            const float2 ms2 = *reinterpret_cast<const float2*>(smask + mbase + t0);
            const float2 mn2 = *reinterpret_cast<const float2*>(nmask + mbase + t0);
            const float msv[2] = { ms2.x, ms2.y };
            const float mnv[2] = { mn2.x, mn2.y };
#pragma unroll
            for (int u = 0; u < 2; ++u) {
                acc[128] += msv[u];
                acc[129] += mnv[u];
#pragma unroll
                for (int m = 0; m < M_MICS; ++m) {
                    const float pd = yr[m][u] * yr[m][u] + yi[m][u] * yi[m][u];
                    acc[UP(m, m)]      += msv[u] * pd;
                    acc[64 + UP(m, m)] += mnv[u] * pd;
#pragma unroll
                    for (int n = m + 1; n < M_MICS; ++n) {
                        const float pr = yr[m][u] * yr[n][u] + yi[m][u] * yi[n][u];
                        const float pi = yi[m][u] * yr[n][u] - yr[m][u] * yi[n][u];
                        acc[UP(m, n)]        += msv[u] * pr;
                        acc[36 + UPI(m, n)]  += msv[u] * pi;
                        acc[64 + UP(m, n)]   += mnv[u] * pr;
                        acc[100 + UPI(m, n)] += mnv[u] * pi;
                    }
                }
            }
        }
    }

#pragma unroll
    for (int c = 0; c < NCHUNK; ++c) {
        float4* dst = reinterpret_cast<float4*>(&sred[tid * 20]);
#pragma unroll
        for (int qq = 0; qq < 4; ++qq) {
            dst[qq] = make_float4(acc[c * 16 + qq * 4 + 0], acc[c * 16 + qq * 4 + 1],
                                  acc[c * 16 + qq * 4 + 2], acc[c * 16 + qq * 4 + 3]);
        }
        __syncthreads();
        {
            const int col = tid & 15, grp = tid >> 4;
            float v = 0.f;
#pragma unroll
            for (int rr = 0; rr < 16; ++rr) v += sred[(grp * 16 + rr) * 20 + col];
            spart[grp * 17 + col] = v;
        }
        __syncthreads();
        if (tid < 16) {
            float v = 0.f;
#pragma unroll
            for (int gp = 0; gp < 16; ++gp) v += spart[gp * 17 + tid];
            sPhi[c * 16 + tid] = v;
        }
        __syncthreads();
    }

    if (tid < 64) {
        const int lane = tid;
        const int r = lane >> 3, cc = lane & 7;
        const float Ssum = sPhi[128] + 1e-8f;
        const float Nsum = sPhi[129] + 1e-8f;
        const int mm = (r < cc) ? r : cc;
        const int nn2 = (r < cc) ? cc : r;
        const int P = mm * 8 - mm * (mm + 1) / 2 + nn2;
        const float sgn = (r <= cc) ? 1.f : -1.f;

        const float ssr = sPhi[P] / Ssum;
        const float ssi = (r == cc) ? 0.f : sgn * sPhi[36 + P - mm - 1] / Ssum;
        float ar = sPhi[64 + P] / Nsum + ((r == cc) ? 1e-5f : 0.f);
        float ai = (r == cc) ? 0.f : sgn * sPhi[100 + P - mm - 1] / Nsum;

        float br = (r == cc) ? 1.f : 0.f, bi = 0.f;
        for (int k = 0; k < 8; ++k) {
            const float pr = __shfl(ar, k * 9, 64);
            const float pi = __shfl(ai, k * 9, 64);
            const float den = pr * pr + pi * pi;
            const float qr = pr / den, qi = -pi / den;
            const bool isk = (r == k);
            const float ar2 = ar * qr - ai * qi;
            const float ai2 = ar * qi + ai * qr;
            const float br2 = br * qr - bi * qi;
            const float bi2 = br * qi + bi * qr;
            ar = isk ? ar2 : ar; ai = isk ? ai2 : ai;
            br = isk ? br2 : br; bi = isk ? bi2 : bi;
            const float rar = __shfl(ar, k * 8 + cc, 64);
            const float rai = __shfl(ai, k * 8 + cc, 64);
            const float rbr = __shfl(br, k * 8 + cc, 64);
            const float rbi = __shfl(bi, k * 8 + cc, 64);
            const float fr = __shfl(ar, r * 8 + k, 64);
            const float fi = __shfl(ai, r * 8 + k, 64);
            const float uar = ar - (fr * rar - fi * rai);
            const float uai = ai - (fr * rai + fi * rar);
            const float ubr = br - (fr * rbr - fi * rbi);
            const float ubi = bi - (fr * rbi + fi * rbr);
            ar = isk ? ar : uar; ai = isk ? ai : uai;
            br = isk ? br : ubr; bi = isk ? bi : ubi;
        }

        float gr = 0.f, gi = 0.f;
        for (int k = 0; k < 8; ++k) {
            const float ir = __shfl(br, r * 8 + k, 64);
            const float ii = __shfl(bi, r * 8 + k, 64);
            const float skr = __shfl(ssr, k * 8 + cc, 64);
            const float ski = __shfl(ssi, k * 8 + cc, 64);
            gr += ir * skr - ii * ski;
            gi += ir * ski + ii * skr;
        }

        float vr = 1.f, vi = 0.f;
        for (int it = 0; it < 30; ++it) {
            float wr2 = gr * vr - gi * vi;
            float wi2 = gr * vi + gi * vr;
            wr2 += __shfl_xor(wr2, 1, 64); wi2 += __shfl_xor(wi2, 1, 64);
            wr2 += __shfl_xor(wr2, 2, 64); wi2 += __shfl_xor(wi2, 2, 64);
            wr2 += __shfl_xor(wr2, 4, 64); wi2 += __shfl_xor(wi2, 4, 64);
            float nrm = wr2 * wr2 + wi2 * wi2;
            nrm += __shfl_xor(nrm, 8, 64);
            nrm += __shfl_xor(nrm, 16, 64);
            nrm += __shfl_xor(nrm, 32, 64);
            const float inv = 1.f / (sqrtf(nrm) + 1e-12f);
            wr2 *= inv; wi2 *= inv;
            vr = __shfl(wr2, cc * 9, 64);
            vi = __shfl(wi2, cc * 9, 64);
        }

        const float v0r = __shfl(vr, 0, 64) + 1e-8f;
        const float v0i = __shfl(vi, 0, 64);
        const float dd = v0r * v0r + v0i * v0i;
        const float rtr = (vr * v0r + vi * v0i) / dd;
        const float rti = (vi * v0r - vr * v0i) / dd;

        float dr = br * rtr - bi * rti;
        float di = br * rti + bi * rtr;
        dr += __shfl_xor(dr, 1, 64); di += __shfl_xor(di, 1, 64);
        dr += __shfl_xor(dr, 2, 64); di += __shfl_xor(di, 2, 64);
        dr += __shfl_xor(dr, 4, 64); di += __shfl_xor(di, 4, 64);

        float q = (r == cc) ? (rtr * dr + rti * di) : 0.f;
        q += __shfl_xor(q, 1, 64); q += __shfl_xor(q, 2, 64); q += __shfl_xor(q, 4, 64);
        q += __shfl_xor(q, 8, 64); q += __shfl_xor(q, 16, 64); q += __shfl_xor(q, 32, 64);
        q += 1e-8f;

        if (cc == 0) {
            sW[r]     = dr / q;
            sW[8 + r] = di / q;
        }
    }
    __syncthreads();

    float wr[M_MICS], wi[M_MICS];
#pragma unroll
    for (int m = 0; m < M_MICS; ++m) { wr[m] = sW[m]; wi[m] = sW[8 + m]; }

    for (int g = 0; g < 4; ++g) {
        const int t0 = g * 512 + 2 * tid;
        if (t0 < T_DIM) {
            float er0 = 0.f, ei0 = 0.f, er1 = 0.f, ei1 = 0.f;
#pragma unroll
            for (int m = 0; m < M_MICS; ++m) {
                const float2 vr2 = *reinterpret_cast<const float2*>(sre + base_bf + (size_t)m * mrow + t0);
                const float2 vi2 = *reinterpret_cast<const float2*>(sim + base_bf + (size_t)m * mrow + t0);
                er0 += wr[m] * vr2.x + wi[m] * vi2.x;
                ei0 += wr[m] * vi2.x - wi[m] * vr2.x;
                er1 += wr[m] * vr2.y + wi[m] * vi2.y;
                ei1 += wr[m] * vi2.y - wi[m] * vr2.y;
            }
            if (out_mode == 2) {
                *reinterpret_cast<float4*>(out + 2 * (mbase + t0)) = make_float4(er0, ei0, er1, ei1);
            } else {
                *reinterpret_cast<float2*>(out + mbase + t0) = make_float2(er0, er1);
            }
        }
    }
}

extern "C" void kernel_launch(void* const* d_in, const int* in_sizes, int n_in,
                              void* d_out, int out_size, void* d_ws, size_t ws_size,
                              hipStream_t stream)
{
    const float* sre   = (const float*)d_in[0];
    const float* sim   = (const float*)d_in[1];
    const float* smask = (const float*)d_in[2];
    const float* nmask = (const float*)d_in[3];
    float* out = (float*)d_out;
    float* ws  = (float*)d_ws;

    const int mode = (out_size >= 2 * B_DIM * F_DIM * T_DIM) ? 2 : 1;

    if (ws_size >= (size_t)WS_FLOATS * sizeof(float)) {
        cov_kernel<<<dim3(F_DIM, B_DIM, NCHUNKT), 256, 0, stream>>>(sre, sim, smask, nmask, ws);
        solve_kernel<<<dim3(NPROB / 4), 256, 0, stream>>>(ws, ws + W_OFFSET);
        apply_kernel<<<dim3(F_DIM, B_DIM, 4), 256, 0, stream>>>(sre, sim, ws + W_OFFSET, out, mode);
    } else {
        mvdr_fused_kernel<<<dim3(F_DIM, B_DIM), 256, 0, stream>>>(sre, sim, smask, nmask, out, mode);
    }
}

// Round 3
// 182.033 us; speedup vs baseline: 1.0385x; 1.0385x over previous
//
#include <hip/hip_runtime.h>

#define B_DIM 8
#define M_MICS 8
#define F_DIM 257
#define T_DIM 2000

// Pair q-index enumeration (m<n):
// m=0: (0,1)..(0,7) q=0..6 ; m=1: q=7..12 ; m=2: q=13..17 ; m=3: q=18..21
// m=4: q=22..24 ; m=5: q=25,26 ; m=6: q=27
// Wave-split of the 130 accumulators:
//  wave0: [0]=msum_s [1]=msum_n [2..9]=ss_diag [10..17]=nn_diag
//         [18+4q+t] for q=0..3 (t: 0=ss_re 1=ss_im 2=nn_re 3=nn_im)   (34)
//  wave1: q=4..11  -> [4*(q-4)+t]    (32)
//  wave2: q=12..19 -> [4*(q-12)+t]   (32)
//  wave3: q=20..27 -> [4*(q-20)+t]   (32)

#define PAIR_ACC(mq, nq, k)                                             \
    {                                                                   \
        const float pr = yr[mq][u] * yr[nq][u] + yi[mq][u] * yi[nq][u]; \
        const float pi = yi[mq][u] * yr[nq][u] - yr[mq][u] * yi[nq][u]; \
        acc[(k) + 0] += msv[u] * pr;                                    \
        acc[(k) + 1] += msv[u] * pi;                                    \
        acc[(k) + 2] += mnv[u] * pr;                                    \
        acc[(k) + 3] += mnv[u] * pi;                                    \
    }

__launch_bounds__(256, 4)
__global__ void mvdr_fused(const float* __restrict__ sre, const float* __restrict__ sim,
                           const float* __restrict__ smask, const float* __restrict__ nmask,
                           float* __restrict__ out, int out_mode)
{
    const int f = blockIdx.x, b = blockIdx.y, tid = threadIdx.x;
    const int h = tid >> 6, l = tid & 63;   // wave id, lane

    __shared__ float sG[4][34];
    __shared__ float sW[16];

    const size_t mrow = (size_t)F_DIM * T_DIM;
    const size_t base_bf = ((size_t)(b * M_MICS) * F_DIM + f) * T_DIM;
    const size_t mbase   = ((size_t)b * F_DIM + f) * T_DIM;

    float acc[34];
#pragma unroll
    for (int i = 0; i < 34; ++i) acc[i] = 0.f;

    // ----------------- covariance accumulation (all 4 waves stream same data) --
#pragma unroll 1
    for (int it = 0; it < 16; ++it) {
        const int t0 = 2 * l + 128 * it;
        if (t0 < T_DIM) {
            float yr[8][2], yi[8][2];
#pragma unroll
            for (int m = 0; m < 8; ++m) {
                const float2 vr = *reinterpret_cast<const float2*>(sre + base_bf + (size_t)m * mrow + t0);
                const float2 vi = *reinterpret_cast<const float2*>(sim + base_bf + (size_t)m * mrow + t0);
                yr[m][0] = vr.x; yr[m][1] = vr.y;
                yi[m][0] = vi.x; yi[m][1] = vi.y;
            }
            const float2 ms2 = *reinterpret_cast<const float2*>(smask + mbase + t0);
            const float2 mn2 = *reinterpret_cast<const float2*>(nmask + mbase + t0);
            const float msv[2] = { ms2.x, ms2.y };
            const float mnv[2] = { mn2.x, mn2.y };

            if (h == 0) {
#pragma unroll
                for (int u = 0; u < 2; ++u) {
                    acc[0] += msv[u];
                    acc[1] += mnv[u];
#pragma unroll
                    for (int m = 0; m < 8; ++m) {
                        const float pd = yr[m][u] * yr[m][u] + yi[m][u] * yi[m][u];
                        acc[2 + m]  += msv[u] * pd;
                        acc[10 + m] += mnv[u] * pd;
                    }
                    PAIR_ACC(0, 1, 18) PAIR_ACC(0, 2, 22) PAIR_ACC(0, 3, 26) PAIR_ACC(0, 4, 30)
                }
            } else if (h == 1) {
#pragma unroll
                for (int u = 0; u < 2; ++u) {
                    PAIR_ACC(0, 5, 0)  PAIR_ACC(0, 6, 4)  PAIR_ACC(0, 7, 8)  PAIR_ACC(1, 2, 12)
                    PAIR_ACC(1, 3, 16) PAIR_ACC(1, 4, 20) PAIR_ACC(1, 5, 24) PAIR_ACC(1, 6, 28)
                }
            } else if (h == 2) {
#pragma unroll
                for (int u = 0; u < 2; ++u) {
                    PAIR_ACC(1, 7, 0)  PAIR_ACC(2, 3, 4)  PAIR_ACC(2, 4, 8)  PAIR_ACC(2, 5, 12)
                    PAIR_ACC(2, 6, 16) PAIR_ACC(2, 7, 20) PAIR_ACC(3, 4, 24) PAIR_ACC(3, 5, 28)
                }
            } else {
#pragma unroll
                for (int u = 0; u < 2; ++u) {
                    PAIR_ACC(3, 6, 0)  PAIR_ACC(3, 7, 4)  PAIR_ACC(4, 5, 8)  PAIR_ACC(4, 6, 12)
                    PAIR_ACC(4, 7, 16) PAIR_ACC(5, 6, 20) PAIR_ACC(5, 7, 24) PAIR_ACC(6, 7, 28)
                }
            }
        }
    }

    // ----------------- per-wave butterfly reduction, lane 0 writes to LDS ------
#pragma unroll
    for (int i = 0; i < 34; ++i) {
        acc[i] += __shfl_xor(acc[i], 1, 64);
        acc[i] += __shfl_xor(acc[i], 2, 64);
        acc[i] += __shfl_xor(acc[i], 4, 64);
        acc[i] += __shfl_xor(acc[i], 8, 64);
        acc[i] += __shfl_xor(acc[i], 16, 64);
        acc[i] += __shfl_xor(acc[i], 32, 64);
    }
    if (l == 0) {
#pragma unroll
        for (int i = 0; i < 34; ++i) sG[h][i] = acc[i];
    }
    __syncthreads();

    // ----------------- solve: wave 0 only, lane = (r, c) of the 8x8 ------------
    if (tid < 64) {
        const int r = tid >> 3, cc = tid & 7;
        const float Ssum = sG[0][0] + 1e-8f;
        const float Nsum = sG[0][1] + 1e-8f;

        float ssr, ssi, ar, ai;
        if (r == cc) {
            ssr = sG[0][2 + r] / Ssum;  ssi = 0.f;
            ar  = sG[0][10 + r] / Nsum + 1e-5f;  ai = 0.f;
        } else {
            const int mm  = (r < cc) ? r : cc;
            const int nn2 = (r < cc) ? cc : r;
            const int q = mm * 8 - mm * (mm + 1) / 2 + nn2 - mm - 1;
            const int g = (q < 4) ? 0 : (1 + ((q - 4) >> 3));
            const int basei = (q < 4) ? (18 + 4 * q) : (4 * ((q - 4) & 7));
            const float sgn = (r < cc) ? 1.f : -1.f;
            ssr = sG[g][basei] / Ssum;
            ssi = sgn * sG[g][basei + 1] / Ssum;
            ar  = sG[g][basei + 2] / Nsum;
            ai  = sgn * sG[g][basei + 3] / Nsum;
        }

        // Gauss-Jordan inverse of Phi_nn (Hermitian PD)
        float br = (r == cc) ? 1.f : 0.f, bi = 0.f;
        for (int k = 0; k < 8; ++k) {
            const float pr = __shfl(ar, k * 9, 64);
            const float pi = __shfl(ai, k * 9, 64);
            const float den = pr * pr + pi * pi;
            const float qr = pr / den, qi = -pi / den;
            const bool isk = (r == k);
            const float ar2 = ar * qr - ai * qi;
            const float ai2 = ar * qi + ai * qr;
            const float br2 = br * qr - bi * qi;
            const float bi2 = br * qi + bi * qr;
            ar = isk ? ar2 : ar; ai = isk ? ai2 : ai;
            br = isk ? br2 : br; bi = isk ? bi2 : bi;
            const float rar = __shfl(ar, k * 8 + cc, 64);
            const float rai = __shfl(ai, k * 8 + cc, 64);
            const float rbr = __shfl(br, k * 8 + cc, 64);
            const float rbi = __shfl(bi, k * 8 + cc, 64);
            const float fr = __shfl(ar, r * 8 + k, 64);
            const float fi = __shfl(ai, r * 8 + k, 64);
            const float uar = ar - (fr * rar - fi * rai);
            const float uai = ai - (fr * rai + fi * rar);
            const float ubr = br - (fr * rbr - fi * rbi);
            const float ubi = bi - (fr * rbi + fi * rbr);
            ar = isk ? ar : uar; ai = isk ? ai : uai;
            br = isk ? br : ubr; bi = isk ? bi : ubi;
        }

        // G = Phi_nn_inv @ Phi_ss
        float gr = 0.f, gi = 0.f;
        for (int k = 0; k < 8; ++k) {
            const float ir = __shfl(br, r * 8 + k, 64);
            const float ii = __shfl(bi, r * 8 + k, 64);
            const float skr = __shfl(ssr, k * 8 + cc, 64);
            const float ski = __shfl(ssi, k * 8 + cc, 64);
            gr += ir * skr - ii * ski;
            gi += ir * ski + ii * skr;
        }

        // power iteration (30 iters)
        float vr = 1.f, vi = 0.f;
        for (int itp = 0; itp < 30; ++itp) {
            float wr2 = gr * vr - gi * vi;
            float wi2 = gr * vi + gi * vr;
            wr2 += __shfl_xor(wr2, 1, 64); wi2 += __shfl_xor(wi2, 1, 64);
            wr2 += __shfl_xor(wr2, 2, 64); wi2 += __shfl_xor(wi2, 2, 64);
            wr2 += __shfl_xor(wr2, 4, 64); wi2 += __shfl_xor(wi2, 4, 64);
            float nrm = wr2 * wr2 + wi2 * wi2;
            nrm += __shfl_xor(nrm, 8, 64);
            nrm += __shfl_xor(nrm, 16, 64);
            nrm += __shfl_xor(nrm, 32, 64);
            const float inv = 1.f / (sqrtf(nrm) + 1e-12f);
            wr2 *= inv; wi2 *= inv;
            vr = __shfl(wr2, cc * 9, 64);
            vi = __shfl(wi2, cc * 9, 64);
        }

        // rtf = v / (v[0] + 1e-8)
        const float v0r = __shfl(vr, 0, 64) + 1e-8f;
        const float v0i = __shfl(vi, 0, 64);
        const float dd = v0r * v0r + v0i * v0i;
        const float rtr = (vr * v0r + vi * v0i) / dd;
        const float rti = (vi * v0r - vr * v0i) / dd;

        // d = Phi_nn_inv @ rtf
        float dr = br * rtr - bi * rti;
        float di = br * rti + bi * rtr;
        dr += __shfl_xor(dr, 1, 64); di += __shfl_xor(di, 1, 64);
        dr += __shfl_xor(dr, 2, 64); di += __shfl_xor(di, 2, 64);
        dr += __shfl_xor(dr, 4, 64); di += __shfl_xor(di, 4, 64);

        float qden = (r == cc) ? (rtr * dr + rti * di) : 0.f;
        qden += __shfl_xor(qden, 1, 64); qden += __shfl_xor(qden, 2, 64);
        qden += __shfl_xor(qden, 4, 64); qden += __shfl_xor(qden, 8, 64);
        qden += __shfl_xor(qden, 16, 64); qden += __shfl_xor(qden, 32, 64);
        qden += 1e-8f;

        if (cc == 0) {
            sW[r]     = dr / qden;
            sW[8 + r] = di / qden;
        }
    }
    __syncthreads();

    // ----------------- apply: enhanced[t] = sum_m conj(w_m) Y[m,t] (L2/L3-hot) --
    float wr[M_MICS], wi[M_MICS];
#pragma unroll
    for (int m = 0; m < M_MICS; ++m) { wr[m] = sW[m]; wi[m] = sW[8 + m]; }

#pragma unroll 1
    for (int g = 0; g < 4; ++g) {
        const int t0 = g * 512 + 2 * tid;
        if (t0 < T_DIM) {
            float er0 = 0.f, ei0 = 0.f, er1 = 0.f, ei1 = 0.f;
#pragma unroll
            for (int m = 0; m < M_MICS; ++m) {
                const float2 vr2 = *reinterpret_cast<const float2*>(sre + base_bf + (size_t)m * mrow + t0);
                const float2 vi2 = *reinterpret_cast<const float2*>(sim + base_bf + (size_t)m * mrow + t0);
                er0 += wr[m] * vr2.x + wi[m] * vi2.x;
                ei0 += wr[m] * vi2.x - wi[m] * vr2.x;
                er1 += wr[m] * vr2.y + wi[m] * vi2.y;
                ei1 += wr[m] * vi2.y - wi[m] * vr2.y;
            }
            if (out_mode == 2) {
                *reinterpret_cast<float4*>(out + 2 * (mbase + t0)) = make_float4(er0, ei0, er1, ei1);
            } else {
                *reinterpret_cast<float2*>(out + mbase + t0) = make_float2(er0, er1);
            }
        }
    }
}

extern "C" void kernel_launch(void* const* d_in, const int* in_sizes, int n_in,
                              void* d_out, int out_size, void* d_ws, size_t ws_size,
                              hipStream_t stream)
{
    const float* sre   = (const float*)d_in[0];
    const float* sim   = (const float*)d_in[1];
    const float* smask = (const float*)d_in[2];
    const float* nmask = (const float*)d_in[3];
    float* out = (float*)d_out;

    const int mode = (out_size >= 2 * B_DIM * F_DIM * T_DIM) ? 2 : 1;

    mvdr_fused<<<dim3(F_DIM, B_DIM), 256, 0, stream>>>(sre, sim, smask, nmask, out, mode);
}

// Round 4
// 161.085 us; speedup vs baseline: 1.1735x; 1.1300x over previous
//
#include <hip/hip_runtime.h>

#define B_DIM 8
#define M_MICS 8
#define F_DIM 257
#define T_DIM 2000
#define NPROB (B_DIM * F_DIM)   // 2056

// Per-problem MVDR weights, written by K1, read by K2 (same launch sequence,
// deterministic every call -> graph-capture safe, no d_ws dependence).
__device__ float g_w[NPROB * 16];

// Pair q-index enumeration (m<n):
// m=0: (0,1)..(0,7) q=0..6 ; m=1: q=7..12 ; m=2: q=13..17 ; m=3: q=18..21
// m=4: q=22..24 ; m=5: q=25,26 ; m=6: q=27
// Wave-split of the 130 accumulators:
//  wave0: [0]=msum_s [1]=msum_n [2..9]=ss_diag [10..17]=nn_diag
//         [18+4q+t] for q=0..3 (t: 0=ss_re 1=ss_im 2=nn_re 3=nn_im)   (34)
//  wave1: q=4..11  -> [4*(q-4)+t]    (32)
//  wave2: q=12..19 -> [4*(q-12)+t]   (32)
//  wave3: q=20..27 -> [4*(q-20)+t]   (32)

#define PAIR_ACC(mq, nq, k)                                             \
    {                                                                   \
        const float pr = yr[mq][u] * yr[nq][u] + yi[mq][u] * yi[nq][u]; \
        const float pi = yi[mq][u] * yr[nq][u] - yr[mq][u] * yi[nq][u]; \
        acc[(k) + 0] += msv[u] * pr;                                    \
        acc[(k) + 1] += msv[u] * pi;                                    \
        acc[(k) + 2] += mnv[u] * pr;                                    \
        acc[(k) + 3] += mnv[u] * pi;                                    \
    }

// ==================== K1: covariance + solve (weights out) ===================
// NOTE: launch_bounds min-waves MUST stay 2 — forcing 4 made the allocator pin
// 64 VGPRs and spill ~80 live floats to scratch (rounds 2+3: WRITE_SIZE 58-116MB).
__launch_bounds__(256, 2)
__global__ void cov_solve_kernel(const float* __restrict__ sre, const float* __restrict__ sim,
                                 const float* __restrict__ smask, const float* __restrict__ nmask)
{
    const int f = blockIdx.x, b = blockIdx.y, tid = threadIdx.x;
    const int h = tid >> 6, l = tid & 63;   // wave id, lane

    __shared__ float sG[4][34];

    const size_t mrow = (size_t)F_DIM * T_DIM;
    const size_t base_bf = ((size_t)(b * M_MICS) * F_DIM + f) * T_DIM;
    const size_t mbase   = ((size_t)b * F_DIM + f) * T_DIM;

    float acc[34];
#pragma unroll
    for (int i = 0; i < 34; ++i) acc[i] = 0.f;

    // ----- covariance accumulation: all 4 waves stream the same samples -------
#pragma unroll 1
    for (int it = 0; it < 16; ++it) {
        const int t0 = 2 * l + 128 * it;
        if (t0 < T_DIM) {
            float yr[8][2], yi[8][2];
#pragma unroll
            for (int m = 0; m < 8; ++m) {
                const float2 vr = *reinterpret_cast<const float2*>(sre + base_bf + (size_t)m * mrow + t0);
                const float2 vi = *reinterpret_cast<const float2*>(sim + base_bf + (size_t)m * mrow + t0);
                yr[m][0] = vr.x; yr[m][1] = vr.y;
                yi[m][0] = vi.x; yi[m][1] = vi.y;
            }
            const float2 ms2 = *reinterpret_cast<const float2*>(smask + mbase + t0);
            const float2 mn2 = *reinterpret_cast<const float2*>(nmask + mbase + t0);
            const float msv[2] = { ms2.x, ms2.y };
            const float mnv[2] = { mn2.x, mn2.y };

            if (h == 0) {
#pragma unroll
                for (int u = 0; u < 2; ++u) {
                    acc[0] += msv[u];
                    acc[1] += mnv[u];
#pragma unroll
                    for (int m = 0; m < 8; ++m) {
                        const float pd = yr[m][u] * yr[m][u] + yi[m][u] * yi[m][u];
                        acc[2 + m]  += msv[u] * pd;
                        acc[10 + m] += mnv[u] * pd;
                    }
                    PAIR_ACC(0, 1, 18) PAIR_ACC(0, 2, 22) PAIR_ACC(0, 3, 26) PAIR_ACC(0, 4, 30)
                }
            } else if (h == 1) {
#pragma unroll
                for (int u = 0; u < 2; ++u) {
                    PAIR_ACC(0, 5, 0)  PAIR_ACC(0, 6, 4)  PAIR_ACC(0, 7, 8)  PAIR_ACC(1, 2, 12)
                    PAIR_ACC(1, 3, 16) PAIR_ACC(1, 4, 20) PAIR_ACC(1, 5, 24) PAIR_ACC(1, 6, 28)
                }
            } else if (h == 2) {
#pragma unroll
                for (int u = 0; u < 2; ++u) {
                    PAIR_ACC(1, 7, 0)  PAIR_ACC(2, 3, 4)  PAIR_ACC(2, 4, 8)  PAIR_ACC(2, 5, 12)
                    PAIR_ACC(2, 6, 16) PAIR_ACC(2, 7, 20) PAIR_ACC(3, 4, 24) PAIR_ACC(3, 5, 28)
                }
            } else {
#pragma unroll
                for (int u = 0; u < 2; ++u) {
                    PAIR_ACC(3, 6, 0)  PAIR_ACC(3, 7, 4)  PAIR_ACC(4, 5, 8)  PAIR_ACC(4, 6, 12)
                    PAIR_ACC(4, 7, 16) PAIR_ACC(5, 6, 20) PAIR_ACC(5, 7, 24) PAIR_ACC(6, 7, 28)
                }
            }
        }
    }

    // ----- per-wave butterfly reduction, lane 0 -> LDS ------------------------
#pragma unroll
    for (int i = 0; i < 34; ++i) {
        acc[i] += __shfl_xor(acc[i], 1, 64);
        acc[i] += __shfl_xor(acc[i], 2, 64);
        acc[i] += __shfl_xor(acc[i], 4, 64);
        acc[i] += __shfl_xor(acc[i], 8, 64);
        acc[i] += __shfl_xor(acc[i], 16, 64);
        acc[i] += __shfl_xor(acc[i], 32, 64);
    }
    if (l == 0) {
#pragma unroll
        for (int i = 0; i < 34; ++i) sG[h][i] = acc[i];
    }
    __syncthreads();

    // ----- solve: wave 0 only, lane = (r, c) of the 8x8 -----------------------
    if (tid < 64) {
        const int r = tid >> 3, cc = tid & 7;
        const float Ssum = sG[0][0] + 1e-8f;
        const float Nsum = sG[0][1] + 1e-8f;

        float ssr, ssi, ar, ai;
        if (r == cc) {
            ssr = sG[0][2 + r] / Ssum;  ssi = 0.f;
            ar  = sG[0][10 + r] / Nsum + 1e-5f;  ai = 0.f;
        } else {
            const int mm  = (r < cc) ? r : cc;
            const int nn2 = (r < cc) ? cc : r;
            const int q = mm * 8 - mm * (mm + 1) / 2 + nn2 - mm - 1;
            const int g = (q < 4) ? 0 : (1 + ((q - 4) >> 3));
            const int basei = (q < 4) ? (18 + 4 * q) : (4 * ((q - 4) & 7));
            const float sgn = (r < cc) ? 1.f : -1.f;
            ssr = sG[g][basei] / Ssum;
            ssi = sgn * sG[g][basei + 1] / Ssum;
            ar  = sG[g][basei + 2] / Nsum;
            ai  = sgn * sG[g][basei + 3] / Nsum;
        }

        // Gauss-Jordan inverse of Phi_nn (Hermitian PD)
        float br = (r == cc) ? 1.f : 0.f, bi = 0.f;
        for (int k = 0; k < 8; ++k) {
            const float pr = __shfl(ar, k * 9, 64);
            const float pi = __shfl(ai, k * 9, 64);
            const float den = pr * pr + pi * pi;
            const float qr = pr / den, qi = -pi / den;
            const bool isk = (r == k);
            const float ar2 = ar * qr - ai * qi;
            const float ai2 = ar * qi + ai * qr;
            const float br2 = br * qr - bi * qi;
            const float bi2 = br * qi + bi * qr;
            ar = isk ? ar2 : ar; ai = isk ? ai2 : ai;
            br = isk ? br2 : br; bi = isk ? bi2 : bi;
            const float rar = __shfl(ar, k * 8 + cc, 64);
            const float rai = __shfl(ai, k * 8 + cc, 64);
            const float rbr = __shfl(br, k * 8 + cc, 64);
            const float rbi = __shfl(bi, k * 8 + cc, 64);
            const float fr = __shfl(ar, r * 8 + k, 64);
            const float fi = __shfl(ai, r * 8 + k, 64);
            const float uar = ar - (fr * rar - fi * rai);
            const float uai = ai - (fr * rai + fi * rar);
            const float ubr = br - (fr * rbr - fi * rbi);
            const float ubi = bi - (fr * rbi + fi * rbr);
            ar = isk ? ar : uar; ai = isk ? ai : uai;
            br = isk ? br : ubr; bi = isk ? bi : ubi;
        }

        // G = Phi_nn_inv @ Phi_ss
        float gr = 0.f, gi = 0.f;
        for (int k = 0; k < 8; ++k) {
            const float ir = __shfl(br, r * 8 + k, 64);
            const float ii = __shfl(bi, r * 8 + k, 64);
            const float skr = __shfl(ssr, k * 8 + cc, 64);
            const float ski = __shfl(ssi, k * 8 + cc, 64);
            gr += ir * skr - ii * ski;
            gi += ir * ski + ii * skr;
        }

        // power iteration (30 iters)
        float vr = 1.f, vi = 0.f;
        for (int itp = 0; itp < 30; ++itp) {
            float wr2 = gr * vr - gi * vi;
            float wi2 = gr * vi + gi * vr;
            wr2 += __shfl_xor(wr2, 1, 64); wi2 += __shfl_xor(wi2, 1, 64);
            wr2 += __shfl_xor(wr2, 2, 64); wi2 += __shfl_xor(wi2, 2, 64);
            wr2 += __shfl_xor(wr2, 4, 64); wi2 += __shfl_xor(wi2, 4, 64);
            float nrm = wr2 * wr2 + wi2 * wi2;
            nrm += __shfl_xor(nrm, 8, 64);
            nrm += __shfl_xor(nrm, 16, 64);
            nrm += __shfl_xor(nrm, 32, 64);
            const float inv = 1.f / (sqrtf(nrm) + 1e-12f);
            wr2 *= inv; wi2 *= inv;
            vr = __shfl(wr2, cc * 9, 64);
            vi = __shfl(wi2, cc * 9, 64);
        }

        // rtf = v / (v[0] + 1e-8)
        const float v0r = __shfl(vr, 0, 64) + 1e-8f;
        const float v0i = __shfl(vi, 0, 64);
        const float dd = v0r * v0r + v0i * v0i;
        const float rtr = (vr * v0r + vi * v0i) / dd;
        const float rti = (vi * v0r - vr * v0i) / dd;

        // d = Phi_nn_inv @ rtf
        float dr = br * rtr - bi * rti;
        float di = br * rti + bi * rtr;
        dr += __shfl_xor(dr, 1, 64); di += __shfl_xor(di, 1, 64);
        dr += __shfl_xor(dr, 2, 64); di += __shfl_xor(di, 2, 64);
        dr += __shfl_xor(dr, 4, 64); di += __shfl_xor(di, 4, 64);

        float qden = (r == cc) ? (rtr * dr + rti * di) : 0.f;
        qden += __shfl_xor(qden, 1, 64); qden += __shfl_xor(qden, 2, 64);
        qden += __shfl_xor(qden, 4, 64); qden += __shfl_xor(qden, 8, 64);
        qden += __shfl_xor(qden, 16, 64); qden += __shfl_xor(qden, 32, 64);
        qden += 1e-8f;

        if (cc == 0) {
            const int p = b * F_DIM + f;
            g_w[p * 16 + r]     = dr / qden;
            g_w[p * 16 + 8 + r] = di / qden;
        }
    }
}

// ============================ K2: apply (pure streaming) =====================
__launch_bounds__(256, 8)
__global__ void apply_kernel(const float* __restrict__ sre, const float* __restrict__ sim,
                             float* __restrict__ out, int out_mode)
{
    const int f = blockIdx.x, b = blockIdx.y, z = blockIdx.z;
    const int tid = threadIdx.x;
    __shared__ float sW[16];
    const int p = b * F_DIM + f;
    if (tid < 16) sW[tid] = g_w[p * 16 + tid];
    __syncthreads();

    const int t0 = z * 512 + 2 * tid;
    if (t0 >= T_DIM) return;

    const size_t mrow = (size_t)F_DIM * T_DIM;
    const size_t base_bf = ((size_t)(b * M_MICS) * F_DIM + f) * T_DIM;
    const size_t mbase   = ((size_t)b * F_DIM + f) * T_DIM;

    float er0 = 0.f, ei0 = 0.f, er1 = 0.f, ei1 = 0.f;
#pragma unroll
    for (int m = 0; m < 8; ++m) {
        const float2 vr2 = *reinterpret_cast<const float2*>(sre + base_bf + (size_t)m * mrow + t0);
        const float2 vi2 = *reinterpret_cast<const float2*>(sim + base_bf + (size_t)m * mrow + t0);
        const float wr = sW[m], wi = sW[8 + m];
        er0 += wr * vr2.x + wi * vi2.x;
        ei0 += wr * vi2.x - wi * vr2.x;
        er1 += wr * vr2.y + wi * vi2.y;
        ei1 += wr * vi2.y - wi * vr2.y;
    }
    if (out_mode == 2) {
        *reinterpret_cast<float4*>(out + 2 * (mbase + t0)) = make_float4(er0, ei0, er1, ei1);
    } else {
        *reinterpret_cast<float2*>(out + mbase + t0) = make_float2(er0, er1);
    }
}

extern "C" void kernel_launch(void* const* d_in, const int* in_sizes, int n_in,
                              void* d_out, int out_size, void* d_ws, size_t ws_size,
                              hipStream_t stream)
{
    const float* sre   = (const float*)d_in[0];
    const float* sim   = (const float*)d_in[1];
    const float* smask = (const float*)d_in[2];
    const float* nmask = (const float*)d_in[3];
    float* out = (float*)d_out;

    const int mode = (out_size >= 2 * B_DIM * F_DIM * T_DIM) ? 2 : 1;

    cov_solve_kernel<<<dim3(F_DIM, B_DIM), 256, 0, stream>>>(sre, sim, smask, nmask);
    apply_kernel<<<dim3(F_DIM, B_DIM, 4), 256, 0, stream>>>(sre, sim, out, mode);
}